// Round 4
// baseline (1187.545 us; speedup 1.0000x reference)
//
#include <hip/hip_runtime.h>
#include <hip/hip_bf16.h>
#include <math.h>

// Problem constants (AydinConfig: H=1024, I=2048, E=8, K=2; B=4, S=2048)
#define NEXP 8
#define HD 1024
#define ID 2048
#define NTOK 8192          // B*S
#define NROWS 16384        // NTOK * top_k

typedef __bf16 bf16_t;
typedef __bf16 bf16x8 __attribute__((ext_vector_type(8)));
typedef float f32x4 __attribute__((ext_vector_type(4)));

// GEMM tiling: 128x64 tile, BK=32, 256 threads (4 waves), each wave 64x32
#define BM 128
#define BN 64
#define BK 32
#define MT_MAX 64          // 8192 / BM worst-case M-tiles per expert

#define GLOBAL_AS __attribute__((address_space(1)))
#define LDS_AS    __attribute__((address_space(3)))

// ---------------------------------------------------------------- router ----
__global__ __launch_bounds__(256)
void router_kernel(const float* __restrict__ x, const float* __restrict__ rw,
                   bf16_t* __restrict__ xb, int* __restrict__ topk_idx,
                   float* __restrict__ topk_w, int* __restrict__ counts)
{
    const int t = blockIdx.x;
    const int tid = threadIdx.x;
    const float4 xv = ((const float4*)(x + (size_t)t * HD))[tid];
    float acc[NEXP];
#pragma unroll
    for (int e = 0; e < NEXP; ++e) {
        const float4 w4 = ((const float4*)(rw + e * HD))[tid];
        acc[e] = xv.x * w4.x + xv.y * w4.y + xv.z * w4.z + xv.w * w4.w;
    }
    // fused fp32 -> bf16 cast of x
    bf16_t tmp[4] = {(bf16_t)xv.x, (bf16_t)xv.y, (bf16_t)xv.z, (bf16_t)xv.w};
    *(uint2*)(xb + (size_t)t * HD + tid * 4) = *(const uint2*)tmp;

    __shared__ float red[4][NEXP];
    const int lane = tid & 63, wv = tid >> 6;
#pragma unroll
    for (int e = 0; e < NEXP; ++e) {
        float v = acc[e];
#pragma unroll
        for (int off = 32; off >= 1; off >>= 1) v += __shfl_down(v, off, 64);
        if (lane == 0) red[wv][e] = v;
    }
    __syncthreads();
    if (tid == 0) {
        float lg[NEXP], mx = -1e30f;
#pragma unroll
        for (int e = 0; e < NEXP; ++e) {
            lg[e] = red[0][e] + red[1][e] + red[2][e] + red[3][e];
            mx = fmaxf(mx, lg[e]);
        }
        float p[NEXP], s = 0.f;
#pragma unroll
        for (int e = 0; e < NEXP; ++e) { p[e] = __expf(lg[e] - mx); s += p[e]; }
        const float inv = 1.f / s;
#pragma unroll
        for (int e = 0; e < NEXP; ++e) p[e] *= inv;
        // top-2, ties -> lower index (matches lax.top_k)
        int i0 = 0; float p0 = p[0];
#pragma unroll
        for (int e = 1; e < NEXP; ++e) if (p[e] > p0) { p0 = p[e]; i0 = e; }
        int i1 = -1; float p1 = -1.f;
#pragma unroll
        for (int e = 0; e < NEXP; ++e) if (e != i0 && p[e] > p1) { p1 = p[e]; i1 = e; }
        const float d = 1.f / (p0 + p1 + 1e-6f);
        topk_idx[t * 2 + 0] = i0; topk_idx[t * 2 + 1] = i1;
        topk_w[t * 2 + 0] = p0 * d; topk_w[t * 2 + 1] = p1 * d;
        atomicAdd(&counts[i0], 1);
        atomicAdd(&counts[i1], 1);
    }
}

// ------------------------------------------------------------------ scan ----
__global__ void scan_kernel(const int* __restrict__ counts,
                            int* __restrict__ offsets, int* __restrict__ cursor)
{
    if (threadIdx.x == 0 && blockIdx.x == 0) {
        int s = 0;
#pragma unroll
        for (int e = 0; e < NEXP; ++e) { offsets[e] = s; cursor[e] = s; s += counts[e]; }
    }
}

// --------------------------------------------------------------- scatter ----
__global__ __launch_bounds__(256)
void scatter_kernel(const int* __restrict__ topk_idx, const float* __restrict__ topk_w,
                    int* __restrict__ cursor, int* __restrict__ token_list,
                    float* __restrict__ row_w)
{
    const int t = blockIdx.x * 256 + threadIdx.x;
    if (t >= NTOK) return;
#pragma unroll
    for (int k = 0; k < 2; ++k) {
        const int e = topk_idx[t * 2 + k];
        const int pos = atomicAdd(&cursor[e], 1);
        token_list[pos] = t;
        row_w[pos] = topk_w[t * 2 + k];
    }
}

// -------------------------------------------------------- precast weights ----
// src: fp32 [K][N] per expert -> dst: bf16 [N][K] per expert (transpose + cast)
__global__ __launch_bounds__(256)
void precast_kernel(const float* __restrict__ src, bf16_t* __restrict__ dst,
                    int K, int N)
{
    const int e = blockIdx.z;
    src += (size_t)e * K * N;
    dst += (size_t)e * K * N;
    const int n0 = blockIdx.x * 64, k0 = blockIdx.y * 64;
    __shared__ float tile[64][65];   // +1 pad: transposed col reads conflict-free
    const int tid = threadIdx.x;
    const int tx = (tid & 15) * 4, ty = tid >> 4;
#pragma unroll
    for (int p = 0; p < 4; ++p) {
        const float4 v = *(const float4*)(src + (size_t)(k0 + ty + p * 16) * N + n0 + tx);
        tile[ty + p * 16][tx + 0] = v.x;
        tile[ty + p * 16][tx + 1] = v.y;
        tile[ty + p * 16][tx + 2] = v.z;
        tile[ty + p * 16][tx + 3] = v.w;
    }
    __syncthreads();
    const int n = tid >> 2, kc = (tid & 3) * 16;
    bf16_t outv[16];
#pragma unroll
    for (int j = 0; j < 16; ++j) outv[j] = (bf16_t)tile[kc + j][n];
    bf16_t* d = dst + (size_t)(n0 + n) * K + k0 + kc;
    *(uint4*)d = *(uint4*)outv;
    *(uint4*)(d + 8) = *((uint4*)outv + 1);
}

// ------------------------------------------------- grouped GEMM1 + SwiGLU ----
// A (gathered x rows) via async global_load_lds into chunk-ordered LDS
// (chunk c=(g*4+i)*4+q)*16+ln -> 16B at c*16; reads lane-contiguous = 0 conflict).
// B (w13b, [n][k] bf16) loaded per-lane DIRECT from global (L2), prefetched.
__global__ __launch_bounds__(256)
void gemm1_kernel(const bf16_t* __restrict__ xb, const bf16_t* __restrict__ w13b,
                  const int* __restrict__ offsets, const int* __restrict__ counts,
                  const int* __restrict__ token_list, bf16_t* __restrict__ hbuf)
{
    const int e = blockIdx.y >> 6;          // / MT_MAX
    const int mt = blockIdx.y & (MT_MAX - 1);
    const int rows = counts[e];
    const int r0 = mt * BM;
    if (r0 >= rows) return;
    const int row_base = offsets[e];
    const int n0 = blockIdx.x * BN;

    __shared__ int tok_s[BM];
    __shared__ alignas(16) bf16_t As[2][BM * BK];   // 2 x 8KB, chunk-ordered

    const int tid = threadIdx.x;
    if (tid < BM) {
        int gr = row_base + r0 + tid;
        if (gr > NROWS - 1) gr = NROWS - 1;   // clamp: padded rows guarded at write
        tok_s[tid] = token_list[gr];
    }
    __syncthreads();

    const int lane = tid & 63, wv = tid >> 6;
    const int wr = wv >> 1, wc = wv & 1;
    const int ln15 = lane & 15, q = lane >> 4;

    // A staging: thread tid owns chunks c0=tid (rows 0-63) and c1=tid+256 (rows 64-127)
    const int ln_a = tid & 15, qa = (tid >> 4) & 3, ia = (tid >> 6) & 3;
    const bf16_t* ga0 = xb + (size_t)tok_s[ia * 16 + ln_a] * HD + qa * 8;
    const bf16_t* ga1 = xb + (size_t)tok_s[64 + ia * 16 + ln_a] * HD + qa * 8;
    bf16_t* dst0 = &As[0][0] + wv * 512;    // wave-uniform; HW adds lane*16B

    // B: per-lane direct fragment pointers (gate; up at +ID*HD)
    const bf16_t* bptr = w13b + (size_t)e * HD * (2 * ID)
                       + (size_t)(n0 + wc * 32 + ln15) * HD + q * 8;

    f32x4 accG[4][2], accU[4][2];
#pragma unroll
    for (int i = 0; i < 4; ++i)
#pragma unroll
        for (int j = 0; j < 2; ++j)
#pragma unroll
            for (int c = 0; c < 4; ++c) { accG[i][j][c] = 0.f; accU[i][j][c] = 0.f; }

    // prologue: stage A(0), load B(0)
    __builtin_amdgcn_global_load_lds((const GLOBAL_AS void*)ga0,
                                     (LDS_AS void*)dst0, 16, 0, 0);
    __builtin_amdgcn_global_load_lds((const GLOBAL_AS void*)ga1,
                                     (LDS_AS void*)(dst0 + 2048), 16, 0, 0);
    bf16x8 bgc[2], buc[2];
#pragma unroll
    for (int j = 0; j < 2; ++j) {
        bgc[j] = *(const bf16x8*)(bptr + (size_t)j * 16 * HD);
        buc[j] = *(const bf16x8*)(bptr + (size_t)ID * HD + (size_t)j * 16 * HD);
    }
    __syncthreads();

    for (int k0 = 0; k0 < HD; k0 += BK) {
        const int buf = (k0 >> 5) & 1;
        bf16x8 bgn[2], bun[2];
        if (k0 + BK < HD) {
            bf16_t* dn = dst0 + (buf ^ 1) * (BM * BK);
            __builtin_amdgcn_global_load_lds((const GLOBAL_AS void*)(ga0 + k0 + BK),
                                             (LDS_AS void*)dn, 16, 0, 0);
            __builtin_amdgcn_global_load_lds((const GLOBAL_AS void*)(ga1 + k0 + BK),
                                             (LDS_AS void*)(dn + 2048), 16, 0, 0);
#pragma unroll
            for (int j = 0; j < 2; ++j) {
                bgn[j] = *(const bf16x8*)(bptr + k0 + BK + (size_t)j * 16 * HD);
                bun[j] = *(const bf16x8*)(bptr + (size_t)ID * HD + k0 + BK + (size_t)j * 16 * HD);
            }
        }
        bf16x8 af[4];
#pragma unroll
        for (int i = 0; i < 4; ++i)
            af[i] = *(const bf16x8*)&As[buf][(wr * 256 + i * 64 + lane) * 8];
#pragma unroll
        for (int i = 0; i < 4; ++i)
#pragma unroll
            for (int j = 0; j < 2; ++j) {
                accG[i][j] = __builtin_amdgcn_mfma_f32_16x16x32_bf16(af[i], bgc[j], accG[i][j], 0, 0, 0);
                accU[i][j] = __builtin_amdgcn_mfma_f32_16x16x32_bf16(af[i], buc[j], accU[i][j], 0, 0, 0);
            }
        __syncthreads();
#pragma unroll
        for (int j = 0; j < 2; ++j) { bgc[j] = bgn[j]; buc[j] = bun[j]; }
    }

    // epilogue: SwiGLU in fp32, store bf16 h. C/D: col=lane&15, row=q*4+reg
#pragma unroll
    for (int i = 0; i < 4; ++i) {
#pragma unroll
        for (int reg = 0; reg < 4; ++reg) {
            const int rr = wr * 64 + i * 16 + q * 4 + reg;
            if (r0 + rr < rows) {
                bf16_t* dst = hbuf + (size_t)(row_base + r0 + rr) * ID + n0 + wc * 32 + ln15;
#pragma unroll
                for (int j = 0; j < 2; ++j) {
                    const float g = accG[i][j][reg], u = accU[i][j][reg];
                    dst[j * 16] = (bf16_t)((g / (1.f + __expf(-g))) * u);
                }
            }
        }
    }
}

// --------------------------------------------------------- grouped GEMM2 ----
// out[token, n] += weight_row * (h_row . w2[e][:, n]); A rows contiguous in hbuf.
__global__ __launch_bounds__(256)
void gemm2_kernel(const bf16_t* __restrict__ hbuf, const bf16_t* __restrict__ w2b,
                  const int* __restrict__ offsets, const int* __restrict__ counts,
                  const int* __restrict__ token_list, const float* __restrict__ row_w,
                  float* __restrict__ out)
{
    const int e = blockIdx.y >> 6;
    const int mt = blockIdx.y & (MT_MAX - 1);
    const int rows = counts[e];
    const int r0 = mt * BM;
    if (r0 >= rows) return;
    const int row_base = offsets[e];
    const int n0 = blockIdx.x * BN;

    __shared__ int tok_s[BM];
    __shared__ float rww_s[BM];
    __shared__ alignas(16) bf16_t As[2][BM * BK];

    const int tid = threadIdx.x;
    if (tid < BM) {
        int gr = row_base + r0 + tid;
        if (gr > NROWS - 1) gr = NROWS - 1;
        tok_s[tid] = token_list[gr];
        rww_s[tid] = row_w[gr];
    }
    __syncthreads();

    const int lane = tid & 63, wv = tid >> 6;
    const int wr = wv >> 1, wc = wv & 1;
    const int ln15 = lane & 15, q = lane >> 4;

    const int ln_a = tid & 15, qa = (tid >> 4) & 3, ia = (tid >> 6) & 3;
    int arow0 = row_base + r0 + ia * 16 + ln_a;
    int arow1 = arow0 + 64;
    if (arow0 > NROWS - 1) arow0 = NROWS - 1;
    if (arow1 > NROWS - 1) arow1 = NROWS - 1;
    const bf16_t* ga0 = hbuf + (size_t)arow0 * ID + qa * 8;
    const bf16_t* ga1 = hbuf + (size_t)arow1 * ID + qa * 8;
    bf16_t* dst0 = &As[0][0] + wv * 512;

    const bf16_t* bptr = w2b + (size_t)e * ID * HD
                       + (size_t)(n0 + wc * 32 + ln15) * ID + q * 8;

    f32x4 acc[4][2];
#pragma unroll
    for (int i = 0; i < 4; ++i)
#pragma unroll
        for (int j = 0; j < 2; ++j)
#pragma unroll
            for (int c = 0; c < 4; ++c) acc[i][j][c] = 0.f;

    __builtin_amdgcn_global_load_lds((const GLOBAL_AS void*)ga0,
                                     (LDS_AS void*)dst0, 16, 0, 0);
    __builtin_amdgcn_global_load_lds((const GLOBAL_AS void*)ga1,
                                     (LDS_AS void*)(dst0 + 2048), 16, 0, 0);
    bf16x8 bc[2];
#pragma unroll
    for (int j = 0; j < 2; ++j)
        bc[j] = *(const bf16x8*)(bptr + (size_t)j * 16 * ID);
    __syncthreads();

    for (int k0 = 0; k0 < ID; k0 += BK) {
        const int buf = (k0 >> 5) & 1;
        bf16x8 bn2[2];
        if (k0 + BK < ID) {
            bf16_t* dn = dst0 + (buf ^ 1) * (BM * BK);
            __builtin_amdgcn_global_load_lds((const GLOBAL_AS void*)(ga0 + k0 + BK),
                                             (LDS_AS void*)dn, 16, 0, 0);
            __builtin_amdgcn_global_load_lds((const GLOBAL_AS void*)(ga1 + k0 + BK),
                                             (LDS_AS void*)(dn + 2048), 16, 0, 0);
#pragma unroll
            for (int j = 0; j < 2; ++j)
                bn2[j] = *(const bf16x8*)(bptr + k0 + BK + (size_t)j * 16 * ID);
        }
        bf16x8 af[4];
#pragma unroll
        for (int i = 0; i < 4; ++i)
            af[i] = *(const bf16x8*)&As[buf][(wr * 256 + i * 64 + lane) * 8];
#pragma unroll
        for (int i = 0; i < 4; ++i)
#pragma unroll
            for (int j = 0; j < 2; ++j)
                acc[i][j] = __builtin_amdgcn_mfma_f32_16x16x32_bf16(af[i], bc[j], acc[i][j], 0, 0, 0);
        __syncthreads();
#pragma unroll
        for (int j = 0; j < 2; ++j) bc[j] = bn2[j];
    }

    // epilogue: scale by routing weight, atomicAdd into out (2 writers/elem)
#pragma unroll
    for (int i = 0; i < 4; ++i) {
#pragma unroll
        for (int reg = 0; reg < 4; ++reg) {
            const int rr = wr * 64 + i * 16 + q * 4 + reg;
            if (r0 + rr < rows) {
                const float w = rww_s[rr];
                float* dst = out + (size_t)tok_s[rr] * HD + n0 + wc * 32 + ln15;
#pragma unroll
                for (int j = 0; j < 2; ++j)
                    atomicAdd(&dst[j * 16], acc[i][j][reg] * w);
            }
        }
    }
}

// ---------------------------------------------------------------- launch ----
extern "C" void kernel_launch(void* const* d_in, const int* in_sizes, int n_in,
                              void* d_out, int out_size, void* d_ws, size_t ws_size,
                              hipStream_t stream) {
    const float* x   = (const float*)d_in[0];   // (4,2048,1024)
    const float* rw  = (const float*)d_in[1];   // (8,1024)
    const float* w13 = (const float*)d_in[2];   // (8,1024,4096)
    const float* w2  = (const float*)d_in[3];   // (8,2048,1024)
    float* out = (float*)d_out;                 // (4,2048,1024) fp32

    char* ws = (char*)d_ws;
    int*   counts     = (int*)(ws + 0);
    int*   cursor     = (int*)(ws + 64);
    int*   offsets    = (int*)(ws + 128);
    int*   topk_idx   = (int*)(ws + 256);
    float* topk_w     = (float*)(ws + 256 + 1 * 65536);
    int*   token_list = (int*)(ws + 256 + 2 * 65536);
    float* row_w      = (float*)(ws + 256 + 3 * 65536);
    const size_t MB = 1024 * 1024;
    bf16_t* xb   = (bf16_t*)(ws + 1 * MB);      // 16 MB
    bf16_t* hbuf = (bf16_t*)(ws + 17 * MB);     // 64 MB
    bf16_t* w13b = (bf16_t*)(ws + 81 * MB);     // 64 MB
    bf16_t* w2b  = (bf16_t*)(ws + 145 * MB);    // 32 MB (ends at 177 MB; R3 confirmed fits)

    hipMemsetAsync(ws, 0, 256, stream);                              // counts/cursor
    hipMemsetAsync(d_out, 0, (size_t)out_size * sizeof(float), stream);

    dim3 gp1(2 * ID / 64, HD / 64, NEXP);   // w13: K=HD, N=2*ID
    precast_kernel<<<gp1, 256, 0, stream>>>(w13, w13b, HD, 2 * ID);
    dim3 gp2(HD / 64, ID / 64, NEXP);       // w2: K=ID, N=HD
    precast_kernel<<<gp2, 256, 0, stream>>>(w2, w2b, ID, HD);

    router_kernel<<<NTOK, 256, 0, stream>>>(x, rw, xb, topk_idx, topk_w, counts);
    scan_kernel<<<1, 64, 0, stream>>>(counts, offsets, cursor);
    scatter_kernel<<<NTOK / 256, 256, 0, stream>>>(topk_idx, topk_w, cursor, token_list, row_w);

    dim3 g1(ID / BN, NEXP * MT_MAX);    // 32 x 512
    gemm1_kernel<<<g1, 256, 0, stream>>>(xb, w13b, offsets, counts, token_list, hbuf);
    dim3 g2(HD / BN, NEXP * MT_MAX);    // 16 x 512
    gemm2_kernel<<<g2, 256, 0, stream>>>(hbuf, w2b, offsets, counts, token_list, row_w, out);
}

// Round 5
// 1025.762 us; speedup vs baseline: 1.1577x; 1.1577x over previous
//
#include <hip/hip_runtime.h>
#include <hip/hip_bf16.h>
#include <math.h>

// Problem constants (AydinConfig: H=1024, I=2048, E=8, K=2; B=4, S=2048)
#define NEXP 8
#define HD 1024
#define ID 2048
#define NTOK 8192          // B*S
#define NROWS 16384        // NTOK * top_k

typedef __bf16 bf16_t;
typedef __bf16 bf16x4 __attribute__((ext_vector_type(4)));
typedef __bf16 bf16x8 __attribute__((ext_vector_type(8)));
typedef float f32x4 __attribute__((ext_vector_type(4)));

// GEMM tiling: 128x64 tile, BK=32, 256 threads (4 waves), each wave 64x32
#define BM 128
#define BN 64
#define BK 32
#define MT_MAX 64          // 8192 / BM worst-case M-tiles per expert

#define GLOBAL_AS __attribute__((address_space(1)))
#define LDS_AS    __attribute__((address_space(3)))

// ---------------------------------------------------------------- router ----
__global__ __launch_bounds__(256)
void router_kernel(const float* __restrict__ x, const float* __restrict__ rw,
                   bf16_t* __restrict__ xb, int* __restrict__ topk_idx,
                   float* __restrict__ topk_w, int* __restrict__ counts)
{
    const int t = blockIdx.x;
    const int tid = threadIdx.x;
    const float4 xv = ((const float4*)(x + (size_t)t * HD))[tid];
    float acc[NEXP];
#pragma unroll
    for (int e = 0; e < NEXP; ++e) {
        const float4 w4 = ((const float4*)(rw + e * HD))[tid];
        acc[e] = xv.x * w4.x + xv.y * w4.y + xv.z * w4.z + xv.w * w4.w;
    }
    // fused fp32 -> bf16 cast of x
    bf16_t tmp[4] = {(bf16_t)xv.x, (bf16_t)xv.y, (bf16_t)xv.z, (bf16_t)xv.w};
    *(uint2*)(xb + (size_t)t * HD + tid * 4) = *(const uint2*)tmp;

    __shared__ float red[4][NEXP];
    const int lane = tid & 63, wv = tid >> 6;
#pragma unroll
    for (int e = 0; e < NEXP; ++e) {
        float v = acc[e];
#pragma unroll
        for (int off = 32; off >= 1; off >>= 1) v += __shfl_down(v, off, 64);
        if (lane == 0) red[wv][e] = v;
    }
    __syncthreads();
    if (tid == 0) {
        float lg[NEXP], mx = -1e30f;
#pragma unroll
        for (int e = 0; e < NEXP; ++e) {
            lg[e] = red[0][e] + red[1][e] + red[2][e] + red[3][e];
            mx = fmaxf(mx, lg[e]);
        }
        float p[NEXP], s = 0.f;
#pragma unroll
        for (int e = 0; e < NEXP; ++e) { p[e] = __expf(lg[e] - mx); s += p[e]; }
        const float inv = 1.f / s;
#pragma unroll
        for (int e = 0; e < NEXP; ++e) p[e] *= inv;
        // top-2, ties -> lower index (matches lax.top_k)
        int i0 = 0; float p0 = p[0];
#pragma unroll
        for (int e = 1; e < NEXP; ++e) if (p[e] > p0) { p0 = p[e]; i0 = e; }
        int i1 = -1; float p1 = -1.f;
#pragma unroll
        for (int e = 0; e < NEXP; ++e) if (e != i0 && p[e] > p1) { p1 = p[e]; i1 = e; }
        const float d = 1.f / (p0 + p1 + 1e-6f);
        topk_idx[t * 2 + 0] = i0; topk_idx[t * 2 + 1] = i1;
        topk_w[t * 2 + 0] = p0 * d; topk_w[t * 2 + 1] = p1 * d;
        atomicAdd(&counts[i0], 1);
        atomicAdd(&counts[i1], 1);
    }
}

// ------------------------------------------------------------------ scan ----
__global__ void scan_kernel(const int* __restrict__ counts,
                            int* __restrict__ offsets, int* __restrict__ cursor)
{
    if (threadIdx.x == 0 && blockIdx.x == 0) {
        int s = 0;
#pragma unroll
        for (int e = 0; e < NEXP; ++e) { offsets[e] = s; cursor[e] = s; s += counts[e]; }
    }
}

// --------------------------------------------------------------- scatter ----
__global__ __launch_bounds__(256)
void scatter_kernel(const int* __restrict__ topk_idx,
                    int* __restrict__ cursor, int* __restrict__ token_list,
                    int* __restrict__ slot_of)
{
    const int t = blockIdx.x * 256 + threadIdx.x;
    if (t >= NTOK) return;
#pragma unroll
    for (int k = 0; k < 2; ++k) {
        const int e = topk_idx[t * 2 + k];
        const int pos = atomicAdd(&cursor[e], 1);
        token_list[pos] = t;
        slot_of[t * 2 + k] = pos;
    }
}

// -------------------------------------------------------- precast weights ----
// src: fp32 [K][N] per expert -> dst: bf16 [N][K] per expert (transpose + cast)
__global__ __launch_bounds__(256)
void precast_kernel(const float* __restrict__ src, bf16_t* __restrict__ dst,
                    int K, int N)
{
    const int e = blockIdx.z;
    src += (size_t)e * K * N;
    dst += (size_t)e * K * N;
    const int n0 = blockIdx.x * 64, k0 = blockIdx.y * 64;
    __shared__ float tile[64][65];   // +1 pad: transposed col reads conflict-free
    const int tid = threadIdx.x;
    const int tx = (tid & 15) * 4, ty = tid >> 4;
#pragma unroll
    for (int p = 0; p < 4; ++p) {
        const float4 v = *(const float4*)(src + (size_t)(k0 + ty + p * 16) * N + n0 + tx);
        tile[ty + p * 16][tx + 0] = v.x;
        tile[ty + p * 16][tx + 1] = v.y;
        tile[ty + p * 16][tx + 2] = v.z;
        tile[ty + p * 16][tx + 3] = v.w;
    }
    __syncthreads();
    const int n = tid >> 2, kc = (tid & 3) * 16;
    bf16_t outv[16];
#pragma unroll
    for (int j = 0; j < 16; ++j) outv[j] = (bf16_t)tile[kc + j][n];
    bf16_t* d = dst + (size_t)(n0 + n) * K + k0 + kc;
    *(uint4*)d = *(uint4*)outv;
    *(uint4*)(d + 8) = *((uint4*)outv + 1);
}

// ------------------------------------------------- grouped GEMM1 + SwiGLU ----
// Both operands staged via async global_load_lds (width 16) into chunk-ordered
// LDS (16B chunk index == fragment-read lane order): all ds ops conflict-free
// (R4 measured 0 conflicts for this A-path). Double-buffered, 1 barrier/k-step.
__global__ __launch_bounds__(256)
void gemm1_kernel(const bf16_t* __restrict__ xb, const bf16_t* __restrict__ w13b,
                  const int* __restrict__ offsets, const int* __restrict__ counts,
                  const int* __restrict__ token_list, bf16_t* __restrict__ hbuf)
{
    const int e = blockIdx.y >> 6;          // / MT_MAX
    const int mt = blockIdx.y & (MT_MAX - 1);
    const int rows = counts[e];
    const int r0 = mt * BM;
    if (r0 >= rows) return;
    const int row_base = offsets[e];
    const int n0 = blockIdx.x * BN;

    __shared__ int tok_s[BM];
    __shared__ alignas(16) bf16_t As[2][BM * BK];   // 2 x 8KB
    __shared__ alignas(16) bf16_t Bgs[2][BN * BK];  // 2 x 4KB
    __shared__ alignas(16) bf16_t Bus[2][BN * BK];  // 2 x 4KB

    const int tid = threadIdx.x;
    if (tid < BM) {
        int gr = row_base + r0 + tid;
        if (gr > NROWS - 1) gr = NROWS - 1;   // clamp: padded rows guarded at write
        tok_s[tid] = token_list[gr];
    }
    __syncthreads();

    const int lane = tid & 63, wv = tid >> 6;
    const int wr = wv >> 1, wc = wv & 1;
    const int ln15 = lane & 15, q = lane >> 4;

    // staging lane decomposition (ln_a = lane&15 row-in-16, qa = k-chunk)
    const int ln_a = tid & 15, qa = (tid >> 4) & 3;
    const bf16_t* ga0 = xb + (size_t)tok_s[wv * 16 + ln_a] * HD + qa * 8;
    const bf16_t* ga1 = xb + (size_t)tok_s[64 + wv * 16 + ln_a] * HD + qa * 8;
    // B staging: wave wv covers n-rows (wv>>1)*32+(wv&1)*16 .. +15 of the tile
    const bf16_t* gbg = w13b + (size_t)e * HD * (2 * ID)
                      + (size_t)(n0 + (wv >> 1) * 32 + (wv & 1) * 16 + ln_a) * HD + qa * 8;
    const bf16_t* gbu = gbg + (size_t)ID * HD;
    bf16_t* adst = &As[0][0] + wv * 512;    // wave-uniform; HW adds lane*16B
    bf16_t* gdst = &Bgs[0][0] + wv * 512;
    bf16_t* udst = &Bus[0][0] + wv * 512;

    f32x4 accG[4][2], accU[4][2];
#pragma unroll
    for (int i = 0; i < 4; ++i)
#pragma unroll
        for (int j = 0; j < 2; ++j)
#pragma unroll
            for (int c = 0; c < 4; ++c) { accG[i][j][c] = 0.f; accU[i][j][c] = 0.f; }

#define STAGE1(buf, k)                                                               \
    do {                                                                             \
        __builtin_amdgcn_global_load_lds((const GLOBAL_AS void*)(ga0 + (k)),         \
            (LDS_AS void*)(adst + (buf) * (BM * BK)), 16, 0, 0);                     \
        __builtin_amdgcn_global_load_lds((const GLOBAL_AS void*)(ga1 + (k)),         \
            (LDS_AS void*)(adst + (buf) * (BM * BK) + 2048), 16, 0, 0);              \
        __builtin_amdgcn_global_load_lds((const GLOBAL_AS void*)(gbg + (k)),         \
            (LDS_AS void*)(gdst + (buf) * (BN * BK)), 16, 0, 0);                     \
        __builtin_amdgcn_global_load_lds((const GLOBAL_AS void*)(gbu + (k)),         \
            (LDS_AS void*)(udst + (buf) * (BN * BK)), 16, 0, 0);                     \
    } while (0)

    STAGE1(0, 0);
    __syncthreads();

    for (int k0 = 0; k0 < HD; k0 += BK) {
        const int buf = (k0 >> 5) & 1;
        if (k0 + BK < HD) STAGE1(buf ^ 1, k0 + BK);

        bf16x8 af[4];
#pragma unroll
        for (int i = 0; i < 4; ++i)
            af[i] = *(const bf16x8*)&As[buf][(wr * 256 + i * 64 + lane) * 8];
        bf16x8 bg[2], bu[2];
#pragma unroll
        for (int j = 0; j < 2; ++j) {
            bg[j] = *(const bf16x8*)&Bgs[buf][((wc * 2 + j) * 64 + lane) * 8];
            bu[j] = *(const bf16x8*)&Bus[buf][((wc * 2 + j) * 64 + lane) * 8];
        }
#pragma unroll
        for (int i = 0; i < 4; ++i)
#pragma unroll
            for (int j = 0; j < 2; ++j) {
                accG[i][j] = __builtin_amdgcn_mfma_f32_16x16x32_bf16(af[i], bg[j], accG[i][j], 0, 0, 0);
                accU[i][j] = __builtin_amdgcn_mfma_f32_16x16x32_bf16(af[i], bu[j], accU[i][j], 0, 0, 0);
            }
        __syncthreads();
    }

    // epilogue: SwiGLU in fp32, store bf16 h. C/D: col=lane&15, row=q*4+reg
#pragma unroll
    for (int i = 0; i < 4; ++i) {
#pragma unroll
        for (int reg = 0; reg < 4; ++reg) {
            const int rr = wr * 64 + i * 16 + q * 4 + reg;
            if (r0 + rr < rows) {
                bf16_t* dst = hbuf + (size_t)(row_base + r0 + rr) * ID + n0 + wc * 32 + ln15;
#pragma unroll
                for (int j = 0; j < 2; ++j) {
                    const float g = accG[i][j][reg], u = accU[i][j][reg];
                    dst[j * 16] = (bf16_t)((g / (1.f + __expf(-g))) * u);
                }
            }
        }
    }
}

// --------------------------------------------------------- grouped GEMM2 ----
// ybuf[row, n] = h_row . w2[e][:, n]  (unscaled; combine applies weights).
// No atomics, no token gather on output.
__global__ __launch_bounds__(256)
void gemm2_kernel(const bf16_t* __restrict__ hbuf, const bf16_t* __restrict__ w2b,
                  const int* __restrict__ offsets, const int* __restrict__ counts,
                  bf16_t* __restrict__ ybuf)
{
    const int e = blockIdx.y >> 6;
    const int mt = blockIdx.y & (MT_MAX - 1);
    const int rows = counts[e];
    const int r0 = mt * BM;
    if (r0 >= rows) return;
    const int row_base = offsets[e];
    const int n0 = blockIdx.x * BN;

    __shared__ alignas(16) bf16_t As[2][BM * BK];
    __shared__ alignas(16) bf16_t Bs[2][BN * BK];

    const int tid = threadIdx.x;
    const int lane = tid & 63, wv = tid >> 6;
    const int wr = wv >> 1, wc = wv & 1;
    const int ln15 = lane & 15, q = lane >> 4;

    const int ln_a = tid & 15, qa = (tid >> 4) & 3;
    int arow0 = row_base + r0 + wv * 16 + ln_a;
    int arow1 = arow0 + 64;
    if (arow0 > NROWS - 1) arow0 = NROWS - 1;
    if (arow1 > NROWS - 1) arow1 = NROWS - 1;
    const bf16_t* ga0 = hbuf + (size_t)arow0 * ID + qa * 8;
    const bf16_t* ga1 = hbuf + (size_t)arow1 * ID + qa * 8;
    const bf16_t* gb = w2b + (size_t)e * ID * HD
                     + (size_t)(n0 + (wv >> 1) * 32 + (wv & 1) * 16 + ln_a) * ID + qa * 8;
    bf16_t* adst = &As[0][0] + wv * 512;
    bf16_t* bdst = &Bs[0][0] + wv * 512;

    f32x4 acc[4][2];
#pragma unroll
    for (int i = 0; i < 4; ++i)
#pragma unroll
        for (int j = 0; j < 2; ++j)
#pragma unroll
            for (int c = 0; c < 4; ++c) acc[i][j][c] = 0.f;

#define STAGE2(buf, k)                                                               \
    do {                                                                             \
        __builtin_amdgcn_global_load_lds((const GLOBAL_AS void*)(ga0 + (k)),         \
            (LDS_AS void*)(adst + (buf) * (BM * BK)), 16, 0, 0);                     \
        __builtin_amdgcn_global_load_lds((const GLOBAL_AS void*)(ga1 + (k)),         \
            (LDS_AS void*)(adst + (buf) * (BM * BK) + 2048), 16, 0, 0);              \
        __builtin_amdgcn_global_load_lds((const GLOBAL_AS void*)(gb + (k)),          \
            (LDS_AS void*)(bdst + (buf) * (BN * BK)), 16, 0, 0);                     \
    } while (0)

    STAGE2(0, 0);
    __syncthreads();

    for (int k0 = 0; k0 < ID; k0 += BK) {
        const int buf = (k0 >> 5) & 1;
        if (k0 + BK < ID) STAGE2(buf ^ 1, k0 + BK);

        bf16x8 af[4];
#pragma unroll
        for (int i = 0; i < 4; ++i)
            af[i] = *(const bf16x8*)&As[buf][(wr * 256 + i * 64 + lane) * 8];
        bf16x8 bf2[2];
#pragma unroll
        for (int j = 0; j < 2; ++j)
            bf2[j] = *(const bf16x8*)&Bs[buf][((wc * 2 + j) * 64 + lane) * 8];
#pragma unroll
        for (int i = 0; i < 4; ++i)
#pragma unroll
            for (int j = 0; j < 2; ++j)
                acc[i][j] = __builtin_amdgcn_mfma_f32_16x16x32_bf16(af[i], bf2[j], acc[i][j], 0, 0, 0);
        __syncthreads();
    }

    // epilogue: contiguous bf16 row writes, unscaled
#pragma unroll
    for (int i = 0; i < 4; ++i) {
#pragma unroll
        for (int reg = 0; reg < 4; ++reg) {
            const int rr = wr * 64 + i * 16 + q * 4 + reg;
            if (r0 + rr < rows) {
                bf16_t* dst = ybuf + (size_t)(row_base + r0 + rr) * HD + n0 + wc * 32 + ln15;
                dst[0]  = (bf16_t)acc[i][0][reg];
                dst[16] = (bf16_t)acc[i][1][reg];
            }
        }
    }
}

// --------------------------------------------------------------- combine ----
// out[t] = w0 * ybuf[slot0(t)] + w1 * ybuf[slot1(t)]
__global__ __launch_bounds__(256)
void combine_kernel(const bf16_t* __restrict__ ybuf, const int* __restrict__ slot_of,
                    const float* __restrict__ topk_w, float* __restrict__ out)
{
    const int t = blockIdx.x;
    const int c = threadIdx.x * 4;
    const int s0 = slot_of[t * 2], s1 = slot_of[t * 2 + 1];
    const float w0 = topk_w[t * 2], w1 = topk_w[t * 2 + 1];
    const bf16x4 a = *(const bf16x4*)(ybuf + (size_t)s0 * HD + c);
    const bf16x4 b = *(const bf16x4*)(ybuf + (size_t)s1 * HD + c);
    float4 o;
    o.x = w0 * (float)a[0] + w1 * (float)b[0];
    o.y = w0 * (float)a[1] + w1 * (float)b[1];
    o.z = w0 * (float)a[2] + w1 * (float)b[2];
    o.w = w0 * (float)a[3] + w1 * (float)b[3];
    *(float4*)(out + (size_t)t * HD + c) = o;
}

// ---------------------------------------------------------------- launch ----
extern "C" void kernel_launch(void* const* d_in, const int* in_sizes, int n_in,
                              void* d_out, int out_size, void* d_ws, size_t ws_size,
                              hipStream_t stream) {
    const float* x   = (const float*)d_in[0];   // (4,2048,1024)
    const float* rw  = (const float*)d_in[1];   // (8,1024)
    const float* w13 = (const float*)d_in[2];   // (8,1024,4096)
    const float* w2  = (const float*)d_in[3];   // (8,2048,1024)
    float* out = (float*)d_out;                 // (4,2048,1024) fp32

    char* ws = (char*)d_ws;
    int*   counts     = (int*)(ws + 0);
    int*   cursor     = (int*)(ws + 64);
    int*   offsets    = (int*)(ws + 128);
    int*   topk_idx   = (int*)(ws + 256);
    float* topk_w     = (float*)(ws + 256 + 1 * 65536);
    int*   token_list = (int*)(ws + 256 + 2 * 65536);
    int*   slot_of    = (int*)(ws + 256 + 3 * 65536);
    const size_t MB = 1024 * 1024;
    bf16_t* xb   = (bf16_t*)(ws + 1 * MB);      // 16 MB
    bf16_t* hbuf = (bf16_t*)(ws + 17 * MB);     // 64 MB
    bf16_t* w13b = (bf16_t*)(ws + 81 * MB);     // 64 MB
    bf16_t* w2b  = (bf16_t*)(ws + 145 * MB);    // 32 MB (ends at 177 MB; fits per R3)
    // ybuf (32 MB) aliases w13b: gemm1 (last reader of w13b) completes before
    // gemm2 writes it (stream order); precast rebuilds w13b every call.
    bf16_t* ybuf = (bf16_t*)(ws + 81 * MB);

    hipMemsetAsync(ws, 0, 256, stream);                              // counts/cursor

    dim3 gp1(2 * ID / 64, HD / 64, NEXP);   // w13: K=HD, N=2*ID
    precast_kernel<<<gp1, 256, 0, stream>>>(w13, w13b, HD, 2 * ID);
    dim3 gp2(HD / 64, ID / 64, NEXP);       // w2: K=ID, N=HD
    precast_kernel<<<gp2, 256, 0, stream>>>(w2, w2b, ID, HD);

    router_kernel<<<NTOK, 256, 0, stream>>>(x, rw, xb, topk_idx, topk_w, counts);
    scan_kernel<<<1, 64, 0, stream>>>(counts, offsets, cursor);
    scatter_kernel<<<NTOK / 256, 256, 0, stream>>>(topk_idx, cursor, token_list, slot_of);

    dim3 g1(ID / BN, NEXP * MT_MAX);    // 32 x 512
    gemm1_kernel<<<g1, 256, 0, stream>>>(xb, w13b, offsets, counts, token_list, hbuf);
    dim3 g2(HD / BN, NEXP * MT_MAX);    // 16 x 512
    gemm2_kernel<<<g2, 256, 0, stream>>>(hbuf, w2b, offsets, counts, ybuf);

    combine_kernel<<<NTOK, 256, 0, stream>>>(ybuf, slot_of, topk_w, out);
}